// Round 7
// baseline (184.528 us; speedup 1.0000x reference)
//
#include <hip/hip_runtime.h>
#include <hip/hip_bf16.h>

#define BATCH 16384
#define IN_F 512
#define OUT_F 512
#define NG 8
#define KTOT (IN_F * NG)   // 4096

// basis_j(x) = exp(-((x-g_j)/h)^2) = 2^(-t_j^2), t_j = t0 - j*s,
//   t0 = SH*x + BC0N, s = SSTEP = sqrt(log2 e) => s^2 = log2 e, 2^(-s^2) = 1/e.
// Separable: basis_j = v0 * rho^j * e^(-j^2), v0 = 2^(-t0^2),
//   rho = exp2(RC1*t0); x-independent e^(-j^2) folded into Wt (QS[]).
#define SH    2.1019642153762872f
#define SSTEP 1.2011224087864498f
#define BC0N  4.2039284307525745f
#define RC1   2.4022448175728996f    // 2s

typedef __attribute__((ext_vector_type(8))) short short8;
typedef __attribute__((ext_vector_type(16))) float f32x16;
typedef __attribute__((ext_vector_type(4))) float f32x4;
typedef __attribute__((ext_vector_type(2))) float f32x2;
typedef __attribute__((ext_vector_type(4))) unsigned int u32x4;
typedef __attribute__((ext_vector_type(2))) unsigned int u32x2;

__device__ __forceinline__ unsigned fbits(float f) {
    union { float f; unsigned u; } v; v.f = f; return v.u;
}
// (lo>>16)|(hi&0xFFFF0000) with rne adds, single v_perm_b32 (fb kernel only).
__device__ __forceinline__ unsigned pack2bf(float lo, float hi) {
    return __builtin_amdgcn_perm(fbits(hi) + 0x8000u, fbits(lo) + 0x8000u,
                                 0x07060302u);
}

// Full A-fragment from ONE x scalar. COMPILER casts (m240: inline-asm
// cvt_pk hurts scheduling); rho^2-parallel chain (serial depth 4, not 7).
// Range: r2 <= 2^81, v0*rho^j <= 2^70 -> finite; underflow -> 0 ok.
__device__ __forceinline__ short8 basis_frag2(float x) {
    const float t0  = fmaf(x, SH, BC0N);
    const float rho = __builtin_amdgcn_exp2f(t0 * RC1);
    const float v0  = __builtin_amdgcn_exp2f(-t0 * t0);
    const float r2  = rho * rho;
    const float v1 = v0 * rho;
    const float v2 = v0 * r2, v3 = v1 * r2;
    const float v4 = v2 * r2, v5 = v3 * r2;
    const float v6 = v4 * r2, v7 = v5 * r2;
    union { __hip_bfloat162 h[4]; short8 s; } u;
    u.h[0] = __float22bfloat162_rn(make_float2(v0, v1));
    u.h[1] = __float22bfloat162_rn(make_float2(v2, v3));
    u.h[2] = __float22bfloat162_rn(make_float2(v4, v5));
    u.h[3] = __float22bfloat162_rn(make_float2(v6, v7));
    return u.s;
}

// ---- prep15: coalesced two-part prep ----
// Part A (blocks 0..511): W -> Wt32 (frag-major B for mfma_f32_32x32x16_bf16)
//   Wt32[((s32*256 + t)*64 + lane)*8 + e] =
//     W[t*16 + (lane>>5)*8 + e][s32*32 + (lane&31)] * e^(-e^2)
//   via LDS: block (kg 0..63, ng 0..7) reads W[kg*64..+64)[ng*64..+64)
//   fully coalesced (f32x4 rows), transposes through LDS, writes 1KB-
//   contiguous frag stores. Replaces the ~72us gather-based wt_swizzle.
// Part B (blocks 512..4607): X -> XtF32 (frag-major x scalars):
//   XtF32[((rb*256 + t)*64 + lane)*2 + mi] =
//     X[rb*64 + mi*32 + (lane&31)][t*2 + (lane>>5)]
__global__ void prep15(const float* __restrict__ W, const float* __restrict__ X,
                       unsigned short* __restrict__ Wt32, float* __restrict__ XtF32) {
    __shared__ float lsf[64 * 68];
    const int tid = threadIdx.x;
    if (blockIdx.x < 512) {
        const int kg = blockIdx.x & 63;      // k-tile of 64 rows
        const int ng = blockIdx.x >> 6;      // n-tile of 64 cols
        // load 64x64 W tile, coalesced (pitch 68 banks-safe)
#pragma unroll
        for (int p = 0; p < 4; ++p) {
            const int row = p * 16 + (tid >> 4);
            const int c4  = (tid & 15) * 4;
            f32x4 v = *(const f32x4*)(W + (size_t)(kg * 64 + row) * OUT_F + ng * 64 + c4);
            *(f32x4*)(&lsf[row * 68 + c4]) = v;
        }
        __syncthreads();
        constexpr float QS[8] = {1.0f,
                                 3.6787944117144233e-1f,   // e^-1
                                 1.8315638888734179e-2f,   // e^-4
                                 1.2340980408667956e-4f,   // e^-9
                                 1.1253517471925912e-7f,   // e^-16
                                 1.3887943864964021e-11f,  // e^-25
                                 2.3195228302435693e-16f,  // e^-36
                                 5.2428856633634640e-22f}; // e^-49
#pragma unroll
        for (int it = 0; it < 2; ++it) {
            const int item = it * 256 + tid;     // 0..511
            const int sl   = item >> 8;          // 0..1
            const int th   = (item >> 6) & 3;    // 0..3
            const int lane = item & 63;
            const int kb   = th * 16 + (lane >> 5) * 8;   // local k base
            const int nc   = sl * 32 + (lane & 31);       // local n col
            union { __hip_bfloat162 h[4]; u32x4 u; } pk;
#pragma unroll
            for (int e = 0; e < 4; ++e)
                pk.h[e] = __float22bfloat162_rn(make_float2(
                    lsf[(kb + 2 * e) * 68 + nc] * QS[2 * e],
                    lsf[(kb + 2 * e + 1) * 68 + nc] * QS[2 * e + 1]));
            const int s32 = 2 * ng + sl;
            const int t   = kg * 4 + th;
            *(u32x4*)(Wt32 + ((size_t)(s32 * 256 + t) * 64 + lane) * 8) = pk.u;
        }
    } else {
        const int bid2 = blockIdx.x - 512;           // 0..4095
        const int rb   = bid2 >> 4;                  // 0..255
        const int g    = bid2 & 15;                  // 16-t group (32 cols)
        const int m0   = rb * 64;
        const int c0   = g * 32;
#pragma unroll
        for (int p = 0; p < 2; ++p) {
            const int idx  = p * 1024 + tid * 4;
            const int row  = idx >> 5;               // 0..63
            const int col4 = idx & 31;               // 0,4,..,28
            f32x4 v = *(const f32x4*)(X + (size_t)(m0 + row) * IN_F + c0 + col4);
            *(f32x4*)(&lsf[row * 36 + col4]) = v;
        }
        __syncthreads();
#pragma unroll
        for (int q = 0; q < 4; ++q) {
            const int p    = q * 256 + tid;          // 0..1023
            const int th   = p >> 6;                 // t-hat 0..15
            const int lane = p & 63;
            const int col  = th * 2 + (lane >> 5);
            f32x2 v;
            v.x = lsf[(lane & 31) * 36 + col];
            v.y = lsf[((lane & 31) + 32) * 36 + col];
            *(f32x2*)(XtF32 + ((size_t)(rb * 256 + g * 16 + th) * 64 + lane) * 2) = v;
        }
    }
}

// ========= R15: R14 free-run + compiler-cast basis + dist-4 prefetch ========
// 256 thr (4 waves), block 64m x 256n, wave 64m x 64n, grid 512. No LDS, no
// barriers (R10/R14: free-run = highest combined pipe-busy). Fixes vs R14:
// (1) compiler bf16 casts, not asm cvt_pk (m240); (2) rho^2 chain halves
// serial depth; (3) 4-slot register rotation = prefetch distance 4 (covers
// L2/HBM latency that dist-1 could not); offsets fold to 0..3KB imm because
// pointers advance once per 4 steps at loop top.
__global__ __launch_bounds__(256, 2) void gauss_gemm15(
        const float* __restrict__ XtF32, const unsigned short* __restrict__ Wt32,
        float* __restrict__ Out) {
    const int tid  = threadIdx.x;
    const int lane = tid & 63;
    const int wave = tid >> 6;
    // XCD-chunked bijective swizzle.
    const int nb = (blockIdx.x & 7) * 64 + (blockIdx.x >> 3);
    const int cb = nb >> 8;          // 0..1
    const int rb = nb & 255;         // 0..255
    const int m0 = rb * 64;
    const int n0 = cb * 256;
    const int s64 = cb * 4 + wave;
    const int s32a = s64 * 2, s32b = s64 * 2 + 1;

    // B: frag for (s32, t) at base + t*512 elems; per-lane offset lane*8.
    const unsigned short* bp0 = Wt32 + (size_t)s32a * 131072 + lane * 8;
    const unsigned short* bp1 = Wt32 + (size_t)s32b * 131072 + lane * 8;
    // A: x-pair for (rb, t) at base + t*128 f32; per-lane offset lane*2.
    const float* ap = XtF32 + (size_t)rb * 32768 + lane * 2;

    f32x16 c00, c01, c10, c11;
#pragma unroll
    for (int e = 0; e < 16; ++e) { c00[e] = 0.f; c01[e] = 0.f; c10[e] = 0.f; c11[e] = 0.f; }

    // 4-slot rotation registers
    f32x2 xa0, xa1, xa2, xa3;
    short8 b0_0, b0_1, b0_2, b0_3, b1_0, b1_1, b1_2, b1_3;

    // prologue: t = 0..3
    xa0 = *(const f32x2*)(ap);        b0_0 = *(const short8*)(bp0);
    b1_0 = *(const short8*)(bp1);
    xa1 = *(const f32x2*)(ap + 128);  b0_1 = *(const short8*)(bp0 + 512);
    b1_1 = *(const short8*)(bp1 + 512);
    xa2 = *(const f32x2*)(ap + 256);  b0_2 = *(const short8*)(bp0 + 1024);
    b1_2 = *(const short8*)(bp1 + 1024);
    xa3 = *(const f32x2*)(ap + 384);  b0_3 = *(const short8*)(bp0 + 1536);
    b1_3 = *(const short8*)(bp1 + 1536);

// Step: basis from slot K (then reload A slot = t+4), 4 MFMA consuming B
// slot K (then reload B slot = t+4). Data deps enforce WAR ordering.
#define STEP15(K)                                                              \
    {                                                                          \
        const short8 a0 = basis_frag2(xa##K.x);                                \
        const short8 a1 = basis_frag2(xa##K.y);                                \
        xa##K = *(const f32x2*)(ap + (K) * 128);                               \
        __builtin_amdgcn_s_setprio(1);                                         \
        c00 = __builtin_amdgcn_mfma_f32_32x32x16_bf16(a0, b0_##K, c00, 0,0,0); \
        c01 = __builtin_amdgcn_mfma_f32_32x32x16_bf16(a0, b1_##K, c01, 0,0,0); \
        c10 = __builtin_amdgcn_mfma_f32_32x32x16_bf16(a1, b0_##K, c10, 0,0,0); \
        c11 = __builtin_amdgcn_mfma_f32_32x32x16_bf16(a1, b1_##K, c11, 0,0,0); \
        __builtin_amdgcn_s_setprio(0);                                         \
        b0_##K = *(const short8*)(bp0 + (K) * 512);                            \
        b1_##K = *(const short8*)(bp1 + (K) * 512);                            \
    }
#define TSTEP15(K)                                                             \
    {                                                                          \
        const short8 a0 = basis_frag2(xa##K.x);                                \
        const short8 a1 = basis_frag2(xa##K.y);                                \
        __builtin_amdgcn_s_setprio(1);                                         \
        c00 = __builtin_amdgcn_mfma_f32_32x32x16_bf16(a0, b0_##K, c00, 0,0,0); \
        c01 = __builtin_amdgcn_mfma_f32_32x32x16_bf16(a0, b1_##K, c01, 0,0,0); \
        c10 = __builtin_amdgcn_mfma_f32_32x32x16_bf16(a1, b0_##K, c10, 0,0,0); \
        c11 = __builtin_amdgcn_mfma_f32_32x32x16_bf16(a1, b1_##K, c11, 0,0,0); \
        __builtin_amdgcn_s_setprio(0);                                         \
    }

    // iter t4: advance to t=4*t4, consume t=4*t4-4..-1, prefetch 4*t4..+3
    for (int t4 = 1; t4 < 64; ++t4) {
        ap  += 512;     // 4 t * 128 f32
        bp0 += 2048;    // 4 t * 512 ushort
        bp1 += 2048;
        STEP15(0)
        STEP15(1)
        STEP15(2)
        STEP15(3)
    }
    // tail: t = 252..255 already in slots
    TSTEP15(0)
    TSTEP15(1)
    TSTEP15(2)
    TSTEP15(3)
#undef STEP15
#undef TSTEP15

    // epilogue: 32x32 C/D layout col=lane&31, row=(e&3)+8*(e>>2)+4*(lane>>5)
    const int ccol = lane & 31;
    const int rof  = 4 * (lane >> 5);
#pragma unroll
    for (int e = 0; e < 16; ++e) {
        const int row = (e & 3) + 8 * (e >> 2) + rof;
        const int c0c = n0 + wave * 64 + ccol;
        Out[(size_t)(m0 + row) * OUT_F + c0c]            = c00[e];
        Out[(size_t)(m0 + row) * OUT_F + c0c + 32]       = c01[e];
        Out[(size_t)(m0 + 32 + row) * OUT_F + c0c]       = c10[e];
        Out[(size_t)(m0 + 32 + row) * OUT_F + c0c + 32]  = c11[e];
    }
}

// ================= fallback (ws too small) =================
#define BM 128
#define BN 128
#define BK 64
#define LDA 72
#define LDB 72

__global__ __launch_bounds__(256, 2) void gauss_gemm_fb(
        const float* __restrict__ X, const float* __restrict__ W,
        float* __restrict__ Out) {
    __shared__ __align__(16) unsigned short sA[BM * LDA];
    __shared__ __align__(16) unsigned short sB2[BN * LDB];

    const int tid  = threadIdx.x;
    const int lane = tid & 63;
    const int wave = tid >> 6;
    const int rb = blockIdx.x >> 2;
    const int cbx = blockIdx.x & 3;
    const int m0 = rb * BM;
    const int n0 = cbx * BN;
    const int wr = (wave >> 1) * 64;
    const int wc = (wave & 1) * 64;
    const int l15 = lane & 15;
    const int lq  = lane >> 4;

    f32x4 acc[4][4];
#pragma unroll
    for (int i = 0; i < 4; ++i)
#pragma unroll
        for (int j = 0; j < 4; ++j)
            acc[i][j] = (f32x4){0.f, 0.f, 0.f, 0.f};

    const int arow = tid & 127;
    const int axq  = tid >> 7;

    for (int kt = 0; kt < KTOT / BK; ++kt) {
        const int k0  = kt * BK;
        const int xc0 = kt * (BK / NG);

        const f32x4 xv = *(const f32x4*)(X + (size_t)(m0 + arow) * IN_F + xc0 + 4 * axq);
        unsigned short* sArow = sA + arow * LDA + axq * 32;
#pragma unroll
        for (int j = 0; j < 4; ++j) {
            const float xs = xv[j] * SH;
            u32x4 pk;
#pragma unroll
            for (int g = 0; g < 8; g += 2) {
                float t0 = xs + (BC0N - g * SSTEP);
                float t1 = xs + (BC0N - (g + 1) * SSTEP);
                pk[g >> 1] = pack2bf(__builtin_amdgcn_exp2f(-t0 * t0),
                                     __builtin_amdgcn_exp2f(-t1 * t1));
            }
            *(u32x4*)(sArow + j * 8) = pk;
        }

#pragma unroll
        for (int p = 0; p < 8; ++p) {
            int id = p * 256 + tid;
            int n  = id & 127;
            int k4 = id >> 7;
            const float* wp = W + (size_t)(k0 + k4 * 4) * OUT_F + n0 + n;
            u32x2 v;
            v[0] = pack2bf(wp[0], wp[OUT_F]);
            v[1] = pack2bf(wp[2 * OUT_F], wp[3 * OUT_F]);
            *(u32x2*)(sB2 + n * LDB + k4 * 4) = v;
        }

        __syncthreads();

#pragma unroll
        for (int kk = 0; kk < BK; kk += 32) {
            short8 af[4], bfv[4];
#pragma unroll
            for (int i = 0; i < 4; ++i)
                af[i] = *(const short8*)(sA + (wr + i * 16 + l15) * LDA + kk + lq * 8);
#pragma unroll
            for (int i = 0; i < 4; ++i)
                bfv[i] = *(const short8*)(sB2 + (wc + i * 16 + l15) * LDB + kk + lq * 8);
#pragma unroll
            for (int i = 0; i < 4; ++i)
#pragma unroll
                for (int j = 0; j < 4; ++j)
                    acc[i][j] = __builtin_amdgcn_mfma_f32_16x16x32_bf16(af[i], bfv[j], acc[i][j], 0, 0, 0);
        }

        __syncthreads();
    }

#pragma unroll
    for (int i = 0; i < 4; ++i) {
        const int r0 = m0 + wr + i * 16 + lq * 4;
#pragma unroll
        for (int j = 0; j < 4; ++j) {
            const int c = n0 + wc + j * 16 + l15;
#pragma unroll
            for (int e = 0; e < 4; ++e)
                Out[(size_t)(r0 + e) * OUT_F + c] = acc[i][j][e];
        }
    }
}

extern "C" void kernel_launch(void* const* d_in, const int* in_sizes, int n_in,
                              void* d_out, int out_size, void* d_ws, size_t ws_size,
                              hipStream_t stream) {
    (void)in_sizes; (void)n_in; (void)out_size;
    const float* X = (const float*)d_in[0];
    // d_in[1] = grid (constants hardcoded: linspace(-2,2,8))
    const float* W = (const float*)d_in[2];
    float* Out = (float*)d_out;

    const size_t xtf_bytes = (size_t)BATCH * IN_F * sizeof(float);           // 32 MB
    const size_t wt_bytes  = (size_t)KTOT * OUT_F * sizeof(unsigned short);  // 4 MB
    if (ws_size >= xtf_bytes + wt_bytes) {
        float* XtF32 = (float*)d_ws;
        unsigned short* Wt32 = (unsigned short*)((char*)d_ws + xtf_bytes);
        prep15<<<dim3(512 + 4096), 256, 0, stream>>>(W, X, Wt32, XtF32);
        gauss_gemm15<<<dim3((BATCH / 64) * (OUT_F / 256)), 256, 0, stream>>>(XtF32, Wt32, Out);
    } else {
        gauss_gemm_fb<<<dim3((BATCH / BM) * (OUT_F / BN)), 256, 0, stream>>>(X, W, Out);
    }
}

// Round 8
// 161.788 us; speedup vs baseline: 1.1406x; 1.1406x over previous
//
#include <hip/hip_runtime.h>
#include <hip/hip_bf16.h>

#define BATCH 16384
#define IN_F 512
#define OUT_F 512
#define NG 8
#define KTOT (IN_F * NG)   // 4096

// basis_j(x) = exp(-((x-g_j)/h)^2) = 2^(-t_j^2), t_j = t0 - j*s,
//   t0 = SH*x + BC0N, s = SSTEP = sqrt(log2 e) => s^2 = log2 e, 2^(-s^2) = 1/e.
// Separable: basis_j = v0 * rho^j * e^(-j^2), v0 = 2^(-t0^2),
//   rho = exp2(RC1*t0); x-independent e^(-j^2) folded into Wt (QS[]).
#define SH    2.1019642153762872f
#define SSTEP 1.2011224087864498f
#define BC0N  4.2039284307525745f
#define RC1   2.4022448175728996f    // 2s

typedef __attribute__((ext_vector_type(8))) short short8;
typedef __attribute__((ext_vector_type(4))) float f32x4;
typedef __attribute__((ext_vector_type(2))) float f32x2;
typedef __attribute__((ext_vector_type(4))) unsigned int u32x4;
typedef __attribute__((ext_vector_type(2))) unsigned int u32x2;

__device__ __forceinline__ unsigned fbits(float f) {
    union { float f; unsigned u; } v; v.f = f; return v.u;
}
// (lo>>16)|(hi&0xFFFF0000) with rne adds, single v_perm_b32.
__device__ __forceinline__ unsigned pack2bf(float lo, float hi) {
    return __builtin_amdgcn_perm(fbits(hi) + 0x8000u, fbits(lo) + 0x8000u,
                                 0x07060302u);
}

// lgkm-only barrier: per-wave lgkmcnt(0) (LDS ops visible) then raw s_barrier.
// B/X register prefetch (vmcnt) survives across it. 0xC07F = vmcnt(63)
// expcnt(7) lgkmcnt(0).
__device__ __forceinline__ void lds_barrier() {
    __asm__ volatile("" ::: "memory");
    __builtin_amdgcn_sched_barrier(0);
    __builtin_amdgcn_s_waitcnt(0xC07F);
    __builtin_amdgcn_s_barrier();
    __builtin_amdgcn_sched_barrier(0);
    __asm__ volatile("" ::: "memory");
}

// ---- prep: W [KTOT][OUT_F] f32 -> Wt_sw bf16 in MFMA-frag-major layout ----
// (proven R0-R4 version; prep cost is ~4-5us, NOT the bottleneck — the
//  ~67us gap between dur_us and gemm time is fixed harness overhead.)
// For s(0..7: n-slice of 64), kt(0..63), f=kk*4+j (0..7), lane(0..63):
//   Wt_sw[ (((s*64+kt)*8+f)*64 + lane)*8 + e ] =
//     W[ kt*64 + kk*32 + (lane>>4)*8 + e ][ s*64 + j*16 + (lane&15) ] * e^(-g^2)
__global__ void wt_swizzle(const float* __restrict__ W, unsigned short* __restrict__ Wt) {
    const int gid  = blockIdx.x * 256 + threadIdx.x;   // 0..262143
    const int lane = gid & 63;
    const int f    = (gid >> 6) & 7;
    const int kt   = (gid >> 9) & 63;
    const int s    = gid >> 15;
    const int j  = f & 3, kk = f >> 2;
    const int l15 = lane & 15, lq = lane >> 4;
    const int n  = s * 64 + j * 16 + l15;
    const int k0 = kt * 64 + kk * 32 + lq * 8;
    constexpr float QS[8] = {1.0f,
                             3.6787944117144233e-1f,   // e^-1
                             1.8315638888734179e-2f,   // e^-4
                             1.2340980408667956e-4f,   // e^-9
                             1.1253517471925912e-7f,   // e^-16
                             1.3887943864964021e-11f,  // e^-25
                             2.3195228302435693e-16f,  // e^-36
                             5.2428856633634640e-22f}; // e^-49
    u32x4 pk;
#pragma unroll
    for (int e = 0; e < 4; ++e)
        pk[e] = pack2bf(W[(size_t)(k0 + 2 * e) * OUT_F + n] * QS[2 * e],
                        W[(size_t)(k0 + 2 * e + 1) * OUT_F + n] * QS[2 * e + 1]);
    *(u32x4*)(Wt + (size_t)gid * 8) = pk;
}

// ====== R17: R12 schedule, 8 waves/block (cross-block barrier coverage) =====
// 512 thr (8 waves), block 64m x 256n, wave 64m x 32n, grid 512 (256rb x 2cb)
// = 2 blocks/CU = 4 waves/SIMD from 2 INDEPENDENT blocks: while one block
// sits at its barrier, the other's waves feed the matrix pipe. Chain work
// HALVES vs R12 (64 rows x 8 features = 512 chains / 512 thr = 1/thread/iter).
// Per-SIMD MFMA demand unchanged (2x waves x half tile). B traffic unchanged
// (scales with Bm=64 only). Ring-8/barrier-4 schedule, XOR swizzle, aofs,
// x-prefetch all carried from R12 (best measured: 77.2us).
__global__ __launch_bounds__(512, 4) void gauss_gemm17(
        const float* __restrict__ X, const unsigned short* __restrict__ Wt,
        float* __restrict__ Out) {
    __shared__ __align__(16) unsigned short sA[8 * 4096];   // 64 KB ring

    const int tid  = threadIdx.x;
    const int lane = tid & 63;
    const int wave = tid >> 6;              // 0..7
    // XCD-chunked bijective swizzle (512 blocks, 64/XCD).
    const int nb = (blockIdx.x & 7) * 64 + (blockIdx.x >> 3);
    const int cb = nb >> 8;                 // 0..1
    const int rb = nb & 255;                // 0..255
    const int m0 = rb * 64;
    const int l15 = lane & 15;
    const int lq  = lane >> 4;
    const int s   = cb * 4 + (wave >> 1);   // 64-col Wt slice
    const int jo  = (wave & 1) * 2;         // 16-col subtile pair in slice

    // A staging: thread (lane, wave) -> row = lane, feature = wave.
    const int aw = lane * 64 + ((wave ^ (lane & 7)) << 3);
    const float* xlp = X + (size_t)(m0 + lane) * IN_F + wave;

    // A frag read offsets: row i*16+l15, feature slot (kk*4+lq)^(l15&7)
    int aofs[2][4];
#pragma unroll
    for (int kk = 0; kk < 2; ++kk)
#pragma unroll
        for (int i = 0; i < 4; ++i)
            aofs[kk][i] = (i * 16 + l15) * 64 + (((kk * 4 + lq) ^ (l15 & 7)) << 3);

    // B source: frag f at tile kt -> bptr + kt*4096 + f*512 (elems);
    // this wave needs f = kk*4 + jo + jj (kk<2, jj<2) -> 4 frags/iter.
    const unsigned short* bptr = Wt + (size_t)s * 262144 + lane * 8;

    f32x4 acc[4][2];
#pragma unroll
    for (int i = 0; i < 4; ++i)
#pragma unroll
        for (int j = 0; j < 2; ++j)
            acc[i][j] = (f32x4){0.f, 0.f, 0.f, 0.f};

    // One chain: v_j = v0 * rho^j (e^{-j^2} lives in Wt); rho^2-parallel,
    // compiler bf16 casts. Range: v0*rho^j <= 2^70 finite; underflow->0 ok.
    auto stageA = [&](float x, int slot) {
        const float t0  = fmaf(x, SH, BC0N);
        const float rho = __builtin_amdgcn_exp2f(t0 * RC1);
        const float v0  = __builtin_amdgcn_exp2f(-t0 * t0);
        const float r2  = rho * rho;
        const float v1 = v0 * rho;
        const float v2 = v0 * r2, v3 = v1 * r2;
        const float v4 = v2 * r2, v5 = v3 * r2;
        const float v6 = v4 * r2, v7 = v5 * r2;
        union { __hip_bfloat162 h[4]; u32x4 u; } pk;
        pk.h[0] = __float22bfloat162_rn(make_float2(v0, v1));
        pk.h[1] = __float22bfloat162_rn(make_float2(v2, v3));
        pk.h[2] = __float22bfloat162_rn(make_float2(v4, v5));
        pk.h[3] = __float22bfloat162_rn(make_float2(v6, v7));
        *(u32x4*)(sA + slot * 4096 + aw) = pk.u;
    };

    short8 bfA[4], bfB[4];
    float xu, xv;   // x prefetch ping-pong (stage distance: loaded 2 iters early)

    // ---- prologue: stage tiles 0..3 -> slots 0..3; xu=x(4), xv=x(5);
    //      bfA = B(0); one barrier. ----
    {
        const float x0 = xlp[0];
        const float x1 = xlp[8];
        const float x2 = xlp[16];
        const float x3 = xlp[24];
        xu = xlp[32];
        xv = xlp[40];
#pragma unroll
        for (int q = 0; q < 4; ++q)
            bfA[q] = *(const short8*)(bptr + ((q >> 1) * 4 + jo + (q & 1)) * 512);
        stageA(x0, 0);
        stageA(x1, 1);
        stageA(x2, 2);
        stageA(x3, 3);
        lds_barrier();
    }

// Sub-iter S (0..7): B prefetch kt+1 -> BF, A-frags from slot S, stage tile
// kt+4 into slot (S+4)&7 using XUSE (=x(kt+4), loaded 2 iters ago), reload
// XUSE with x(kt+6), 8 MFMA under setprio. Barrier when S&3==3.
// Race ledger (as R12): read slot kt&7, write slot (kt+4)&7, skew<4 =>
// write-slot in read-slot+{1..7} mod 8; write->read dist 4 crosses 1 barrier.
#define GG17(KT0, S, BU, BF, XUSE)                                             \
    {                                                                          \
        const int kt  = (KT0) + (S);                                           \
        const int kn1 = (kt + 1 < 64) ? kt + 1 : 63;                           \
        const int kn6 = (kt + 6 < 64) ? kt + 6 : 63;                           \
        _Pragma("unroll")                                                      \
        for (int q = 0; q < 4; ++q)                                            \
            BF[q] = *(const short8*)(bptr + (size_t)kn1 * 4096 +               \
                                     ((q >> 1) * 4 + jo + (q & 1)) * 512);     \
        short8 af[2][4];                                                       \
        _Pragma("unroll")                                                      \
        for (int kk = 0; kk < 2; ++kk)                                         \
            _Pragma("unroll")                                                  \
            for (int i = 0; i < 4; ++i)                                        \
                af[kk][i] = *(const short8*)(sA + (S) * 4096 + aofs[kk][i]);   \
        stageA(XUSE, ((S) + 4) & 7);                                           \
        XUSE = xlp[(size_t)kn6 * 8];                                           \
        __builtin_amdgcn_s_setprio(1);                                         \
        _Pragma("unroll")                                                      \
        for (int kk = 0; kk < 2; ++kk)                                         \
            _Pragma("unroll")                                                  \
            for (int i = 0; i < 4; ++i)                                        \
                _Pragma("unroll")                                              \
                for (int j = 0; j < 2; ++j)                                    \
                    acc[i][j] = __builtin_amdgcn_mfma_f32_16x16x32_bf16(       \
                        af[kk][i], BU[kk * 2 + j], acc[i][j], 0, 0, 0);        \
        __builtin_amdgcn_s_setprio(0);                                         \
        if (((S) & 3) == 3) lds_barrier();                                     \
    }

    for (int kt0 = 0; kt0 < 64; kt0 += 8) {
        GG17(kt0, 0, bfA, bfB, xu)
        GG17(kt0, 1, bfB, bfA, xv)
        GG17(kt0, 2, bfA, bfB, xu)
        GG17(kt0, 3, bfB, bfA, xv)
        GG17(kt0, 4, bfA, bfB, xu)
        GG17(kt0, 5, bfB, bfA, xv)
        GG17(kt0, 6, bfA, bfB, xu)
        GG17(kt0, 7, bfB, bfA, xv)
    }
#undef GG17

    // ---- epilogue: C/D layout col=lane&15, row=(lane>>4)*4+e ----
#pragma unroll
    for (int i = 0; i < 4; ++i) {
        const int r0 = m0 + i * 16 + lq * 4;
#pragma unroll
        for (int j = 0; j < 2; ++j) {
            const int c = cb * 256 + (wave >> 1) * 64 + (jo + j) * 16 + l15;
#pragma unroll
            for (int e = 0; e < 4; ++e)
                Out[(size_t)(r0 + e) * OUT_F + c] = acc[i][j][e];
        }
    }
}

// ================= fallback (ws too small for Wt) =================
#define BM 128
#define BN 128
#define BK 64
#define LDA 72
#define LDB 72

__global__ __launch_bounds__(256, 2) void gauss_gemm_fb(
        const float* __restrict__ X, const float* __restrict__ W,
        float* __restrict__ Out) {
    __shared__ __align__(16) unsigned short sA[BM * LDA];
    __shared__ __align__(16) unsigned short sB2[BN * LDB];

    const int tid  = threadIdx.x;
    const int lane = tid & 63;
    const int wave = tid >> 6;
    const int rb = blockIdx.x >> 2;
    const int cbx = blockIdx.x & 3;
    const int m0 = rb * BM;
    const int n0 = cbx * BN;
    const int wr = (wave >> 1) * 64;
    const int wc = (wave & 1) * 64;
    const int l15 = lane & 15;
    const int lq  = lane >> 4;

    f32x4 acc[4][4];
#pragma unroll
    for (int i = 0; i < 4; ++i)
#pragma unroll
        for (int j = 0; j < 4; ++j)
            acc[i][j] = (f32x4){0.f, 0.f, 0.f, 0.f};

    const int arow = tid & 127;
    const int axq  = tid >> 7;

    for (int kt = 0; kt < KTOT / BK; ++kt) {
        const int k0  = kt * BK;
        const int xc0 = kt * (BK / NG);

        const f32x4 xv = *(const f32x4*)(X + (size_t)(m0 + arow) * IN_F + xc0 + 4 * axq);
        unsigned short* sArow = sA + arow * LDA + axq * 32;
#pragma unroll
        for (int j = 0; j < 4; ++j) {
            const float xs = xv[j] * SH;
            u32x4 pk;
#pragma unroll
            for (int g = 0; g < 8; g += 2) {
                float t0 = xs + (BC0N - g * SSTEP);
                float t1 = xs + (BC0N - (g + 1) * SSTEP);
                pk[g >> 1] = pack2bf(__builtin_amdgcn_exp2f(-t0 * t0),
                                     __builtin_amdgcn_exp2f(-t1 * t1));
            }
            *(u32x4*)(sArow + j * 8) = pk;
        }

#pragma unroll
        for (int p = 0; p < 8; ++p) {
            int id = p * 256 + tid;
            int n  = id & 127;
            int k4 = id >> 7;
            const float* wp = W + (size_t)(k0 + k4 * 4) * OUT_F + n0 + n;
            u32x2 v;
            v[0] = pack2bf(wp[0], wp[OUT_F]);
            v[1] = pack2bf(wp[2 * OUT_F], wp[3 * OUT_F]);
            *(u32x2*)(sB2 + n * LDB + k4 * 4) = v;
        }

        __syncthreads();

#pragma unroll
        for (int kk = 0; kk < BK; kk += 32) {
            short8 af[4], bfv[4];
#pragma unroll
            for (int i = 0; i < 4; ++i)
                af[i] = *(const short8*)(sA + (wr + i * 16 + l15) * LDA + kk + lq * 8);
#pragma unroll
            for (int i = 0; i < 4; ++i)
                bfv[i] = *(const short8*)(sB2 + (wc + i * 16 + l15) * LDB + kk + lq * 8);
#pragma unroll
            for (int i = 0; i < 4; ++i)
#pragma unroll
                for (int j = 0; j < 4; ++j)
                    acc[i][j] = __builtin_amdgcn_mfma_f32_16x16x32_bf16(af[i], bfv[j], acc[i][j], 0, 0, 0);
        }

        __syncthreads();
    }

#pragma unroll
    for (int i = 0; i < 4; ++i) {
        const int r0 = m0 + wr + i * 16 + lq * 4;
#pragma unroll
        for (int j = 0; j < 4; ++j) {
            const int c = n0 + wc + j * 16 + l15;
#pragma unroll
            for (int e = 0; e < 4; ++e)
                Out[(size_t)(r0 + e) * OUT_F + c] = acc[i][j][e];
        }
    }
}

extern "C" void kernel_launch(void* const* d_in, const int* in_sizes, int n_in,
                              void* d_out, int out_size, void* d_ws, size_t ws_size,
                              hipStream_t stream) {
    (void)in_sizes; (void)n_in; (void)out_size;
    const float* X = (const float*)d_in[0];
    // d_in[1] = grid (constants hardcoded: linspace(-2,2,8))
    const float* W = (const float*)d_in[2];
    float* Out = (float*)d_out;

    const size_t wt_bytes = (size_t)KTOT * OUT_F * sizeof(unsigned short); // 4 MB
    if (ws_size >= wt_bytes) {
        unsigned short* Wt = (unsigned short*)d_ws;
        wt_swizzle<<<dim3(KTOT * OUT_F / 8 / 256), 256, 0, stream>>>(W, Wt);
        gauss_gemm17<<<dim3((BATCH / 64) * (OUT_F / 256)), 512, 0, stream>>>(X, Wt, Out);
    } else {
        gauss_gemm_fb<<<dim3((BATCH / BM) * (OUT_F / BN)), 256, 0, stream>>>(X, W, Out);
    }
}

// Round 9
// 154.712 us; speedup vs baseline: 1.1927x; 1.0457x over previous
//
#include <hip/hip_runtime.h>
#include <hip/hip_bf16.h>

#define BATCH 16384
#define IN_F 512
#define OUT_F 512
#define NG 8
#define KTOT (IN_F * NG)   // 4096

// basis_j(x) = exp(-((x-g_j)/h)^2) = 2^(-t_j^2), t_j = t0 - j*s,
//   t0 = SH*x + BC0N, s = SSTEP = sqrt(log2 e) => s^2 = log2 e, 2^(-s^2) = 1/e.
// Separable: basis_j = v0 * rho^j * e^(-j^2), v0 = 2^(-t0^2),
//   rho = exp2(RC1*t0); x-independent e^(-j^2) folded into Wt (QS[]).
#define SH    2.1019642153762872f
#define SSTEP 1.2011224087864498f
#define BC0N  4.2039284307525745f
#define RC1   2.4022448175728996f    // 2s

typedef __attribute__((ext_vector_type(8))) short short8;
typedef __attribute__((ext_vector_type(4))) float f32x4;
typedef __attribute__((ext_vector_type(2))) float f32x2;
typedef __attribute__((ext_vector_type(4))) unsigned int u32x4;
typedef __attribute__((ext_vector_type(2))) unsigned int u32x2;

__device__ __forceinline__ unsigned fbits(float f) {
    union { float f; unsigned u; } v; v.f = f; return v.u;
}
// (lo>>16)|(hi&0xFFFF0000) with rne adds, single v_perm_b32.
__device__ __forceinline__ unsigned pack2bf(float lo, float hi) {
    return __builtin_amdgcn_perm(fbits(hi) + 0x8000u, fbits(lo) + 0x8000u,
                                 0x07060302u);
}

// lgkm-only barrier: per-wave lgkmcnt(0) (LDS ops visible) then raw s_barrier.
// B/X register prefetch (vmcnt) survives across it. 0xC07F = vmcnt(63)
// expcnt(7) lgkmcnt(0).
__device__ __forceinline__ void lds_barrier() {
    __asm__ volatile("" ::: "memory");
    __builtin_amdgcn_sched_barrier(0);
    __builtin_amdgcn_s_waitcnt(0xC07F);
    __builtin_amdgcn_s_barrier();
    __builtin_amdgcn_sched_barrier(0);
    __asm__ volatile("" ::: "memory");
}

// ---- prep: W [KTOT][OUT_F] f32 -> Wt_sw bf16 in MFMA-frag-major layout ----
// For s(0..7: n-slice of 64), kt(0..63), f=kk*4+j (0..7), lane(0..63):
//   Wt_sw[ (((s*64+kt)*8+f)*64 + lane)*8 + e ] =
//     W[ kt*64 + kk*32 + (lane>>4)*8 + e ][ s*64 + j*16 + (lane&15) ] * e^(-g^2)
__global__ void wt_swizzle(const float* __restrict__ W, unsigned short* __restrict__ Wt) {
    const int gid  = blockIdx.x * 256 + threadIdx.x;   // 0..262143
    const int lane = gid & 63;
    const int f    = (gid >> 6) & 7;
    const int kt   = (gid >> 9) & 63;
    const int s    = gid >> 15;
    const int j  = f & 3, kk = f >> 2;
    const int l15 = lane & 15, lq = lane >> 4;
    const int n  = s * 64 + j * 16 + l15;
    const int k0 = kt * 64 + kk * 32 + lq * 8;
    constexpr float QS[8] = {1.0f,
                             3.6787944117144233e-1f,   // e^-1
                             1.8315638888734179e-2f,   // e^-4
                             1.2340980408667956e-4f,   // e^-9
                             1.1253517471925912e-7f,   // e^-16
                             1.3887943864964021e-11f,  // e^-25
                             2.3195228302435693e-16f,  // e^-36
                             5.2428856633634640e-22f}; // e^-49
    u32x4 pk;
#pragma unroll
    for (int e = 0; e < 4; ++e)
        pk[e] = pack2bf(W[(size_t)(k0 + 2 * e) * OUT_F + n] * QS[2 * e],
                        W[(size_t)(k0 + 2 * e + 1) * OUT_F + n] * QS[2 * e + 1]);
    *(u32x4*)(Wt + (size_t)gid * 8) = pk;
}

// ====== R18: R12 schedule scaled to Bm=128 (halve L2 B-traffic per FLOP) ====
// 512 thr (8 waves, 2M x 4N), block 128m x 256n, wave 64m x 64n -- per-wave
// work IDENTICAL to R12 (8 B-frags, 8 A-frags, 32 MFMA, 2 chains/thread/tile).
// grid 256 = 1 block/CU. Cycle accounting (per SIMD per K64) said R12's L2
// B-read (1170cyc) co-binds with MFMA pipe (1242cyc); Bm 64->128 halves
// B-bytes/FLOP -> L2 term ~585cyc, MFMA unchanged. Chain count unchanged
// (scales with Bn only). Ring-8 x 16KB = 128KB LDS, stage-4-ahead, lgkm-only
// barrier every 4. launch_bounds(512,2): VGPR cap 256 (R13/R17 trap: any
// occupancy bound >=4 forces VGPR<=64 and kills prefetch ILP).
__global__ __launch_bounds__(512, 2) void gauss_gemm18(
        const float* __restrict__ X, const unsigned short* __restrict__ Wt,
        float* __restrict__ Out) {
    __shared__ __align__(16) unsigned short sA[8 * 8192];   // 128 KB ring

    const int tid  = threadIdx.x;
    const int lane = tid & 63;
    const int wave = tid >> 6;              // 0..7
    const int wm   = wave >> 2;             // 0..1  (m half)
    const int wn   = wave & 3;              // 0..3  (n slice)
    // XCD-chunked bijective swizzle: 256 blocks, 32/XCD; cb constant per XCD.
    const int nb = (blockIdx.x & 7) * 32 + (blockIdx.x >> 3);
    const int cb = nb >> 7;                 // 0..1
    const int rb = nb & 127;                // 0..127
    const int m0 = rb * 128;
    const int l15 = lane & 15;
    const int lq  = lane >> 4;
    const int s   = cb * 4 + wn;            // 64-col Wt slice for this wave

    // A staging: thread t -> row = t&127, feature pair fp = t>>7 (0..3):
    // features 2fp, 2fp+1. XOR swizzle by (row&7) as in R12.
    const int arow = tid & 127;
    const int fp   = tid >> 7;
    const int aw0 = arow * 64 + (((2 * fp)     ^ (arow & 7)) << 3);
    const int aw1 = arow * 64 + (((2 * fp + 1) ^ (arow & 7)) << 3);
    const float* xlp = X + (size_t)(m0 + arow) * IN_F + fp * 2;

    // A frag read offsets: row wm*64 + i*16 + l15, slot (kk*4+lq)^(l15&7)
    // (row&7 == l15&7, consistent with staging XOR).
    int aofs[2][4];
#pragma unroll
    for (int kk = 0; kk < 2; ++kk)
#pragma unroll
        for (int i = 0; i < 4; ++i)
            aofs[kk][i] = (wm * 64 + i * 16 + l15) * 64 +
                          (((kk * 4 + lq) ^ (l15 & 7)) << 3);

    // B source: frag f at tile kt -> bptr + kt*4096 + f*512 (elems)
    const unsigned short* bptr = Wt + (size_t)s * 262144 + lane * 8;

    f32x4 acc[4][4];
#pragma unroll
    for (int i = 0; i < 4; ++i)
#pragma unroll
        for (int j = 0; j < 4; ++j)
            acc[i][j] = (f32x4){0.f, 0.f, 0.f, 0.f};

    // Two chains (features 2fp, 2fp+1) -> one u32x4 LDS store each.
    // v_j = v0 * rho^j (e^{-j^2} lives in Wt); rho^2-parallel chain.
    auto stageA = [&](f32x2 xv, int slot) {
        unsigned short* base = sA + slot * 8192;
#pragma unroll
        for (int h = 0; h < 2; ++h) {
            const float t0  = fmaf(h ? xv.y : xv.x, SH, BC0N);
            const float rho = __builtin_amdgcn_exp2f(t0 * RC1);
            const float v0  = __builtin_amdgcn_exp2f(-t0 * t0);
            const float r2  = rho * rho;
            const float v1 = v0 * rho;
            const float v2 = v0 * r2, v3 = v1 * r2;
            const float v4 = v2 * r2, v5 = v3 * r2;
            const float v6 = v4 * r2, v7 = v5 * r2;
            union { __hip_bfloat162 hh[4]; u32x4 u; } pk;
            pk.hh[0] = __float22bfloat162_rn(make_float2(v0, v1));
            pk.hh[1] = __float22bfloat162_rn(make_float2(v2, v3));
            pk.hh[2] = __float22bfloat162_rn(make_float2(v4, v5));
            pk.hh[3] = __float22bfloat162_rn(make_float2(v6, v7));
            *(u32x4*)(base + (h ? aw1 : aw0)) = pk.u;
        }
    };

    short8 bfA[8], bfB[8];
    f32x2 xu, xv;   // x prefetch ping-pong (loaded 2 iters before staging)

    // ---- prologue: stage tiles 0..3 -> slots 0..3; xu=x(4), xv=x(5);
    //      bfA = B(0); one barrier. ----
    {
        f32x2 x0 = *(const f32x2*)(xlp);
        f32x2 x1 = *(const f32x2*)(xlp + 8);
        f32x2 x2 = *(const f32x2*)(xlp + 16);
        f32x2 x3 = *(const f32x2*)(xlp + 24);
        xu = *(const f32x2*)(xlp + 32);
        xv = *(const f32x2*)(xlp + 40);
#pragma unroll
        for (int f = 0; f < 8; ++f)
            bfA[f] = *(const short8*)(bptr + f * 512);
        stageA(x0, 0);
        stageA(x1, 1);
        stageA(x2, 2);
        stageA(x3, 3);
        lds_barrier();
    }

// Sub-iter S (0..7): B prefetch kt+1 -> BF, A-frags from slot S, stage tile
// kt+4 into slot (S+4)&7 using XUSE (=x(kt+4), loaded 2 iters ago), reload
// XUSE with x(kt+6), 32 MFMA under setprio. Barrier when S&3==3.
// Race ledger (as R12): read slot kt&7, write slot (kt+4)&7, skew<4 =>
// write-slot in read-slot+{1..7} mod 8; write->read dist 4 crosses 1 barrier.
#define GG18(KT0, S, BU, BF, XUSE)                                             \
    {                                                                          \
        const int kt  = (KT0) + (S);                                           \
        const int kn1 = (kt + 1 < 64) ? kt + 1 : 63;                           \
        const int kn6 = (kt + 6 < 64) ? kt + 6 : 63;                           \
        _Pragma("unroll")                                                      \
        for (int f = 0; f < 8; ++f)                                            \
            BF[f] = *(const short8*)(bptr + (size_t)kn1 * 4096 + f * 512);     \
        short8 af[2][4];                                                       \
        _Pragma("unroll")                                                      \
        for (int kk = 0; kk < 2; ++kk)                                         \
            _Pragma("unroll")                                                  \
            for (int i = 0; i < 4; ++i)                                        \
                af[kk][i] = *(const short8*)(sA + (S) * 8192 + aofs[kk][i]);   \
        stageA(XUSE, ((S) + 4) & 7);                                           \
        XUSE = *(const f32x2*)(xlp + (size_t)kn6 * 8);                         \
        __builtin_amdgcn_s_setprio(1);                                         \
        _Pragma("unroll")                                                      \
        for (int kk = 0; kk < 2; ++kk)                                         \
            _Pragma("unroll")                                                  \
            for (int i = 0; i < 4; ++i)                                        \
                _Pragma("unroll")                                              \
                for (int j = 0; j < 4; ++j)                                    \
                    acc[i][j] = __builtin_amdgcn_mfma_f32_16x16x32_bf16(       \
                        af[kk][i], BU[kk * 4 + j], acc[i][j], 0, 0, 0);        \
        __builtin_amdgcn_s_setprio(0);                                         \
        if (((S) & 3) == 3) lds_barrier();                                     \
    }

    for (int kt0 = 0; kt0 < 64; kt0 += 8) {
        GG18(kt0, 0, bfA, bfB, xu)
        GG18(kt0, 1, bfB, bfA, xv)
        GG18(kt0, 2, bfA, bfB, xu)
        GG18(kt0, 3, bfB, bfA, xv)
        GG18(kt0, 4, bfA, bfB, xu)
        GG18(kt0, 5, bfB, bfA, xv)
        GG18(kt0, 6, bfA, bfB, xu)
        GG18(kt0, 7, bfB, bfA, xv)
    }
#undef GG18

    // ---- epilogue: C/D layout col=lane&15, row=(lane>>4)*4+e ----
#pragma unroll
    for (int i = 0; i < 4; ++i) {
        const int r0 = m0 + wm * 64 + i * 16 + lq * 4;
#pragma unroll
        for (int j = 0; j < 4; ++j) {
            const int c = cb * 256 + wn * 64 + j * 16 + l15;
#pragma unroll
            for (int e = 0; e < 4; ++e)
                Out[(size_t)(r0 + e) * OUT_F + c] = acc[i][j][e];
        }
    }
}

// ================= fallback (ws too small for Wt) =================
#define BM 128
#define BN 128
#define BK 64
#define LDA 72
#define LDB 72

__global__ __launch_bounds__(256, 2) void gauss_gemm_fb(
        const float* __restrict__ X, const float* __restrict__ W,
        float* __restrict__ Out) {
    __shared__ __align__(16) unsigned short sA[BM * LDA];
    __shared__ __align__(16) unsigned short sB2[BN * LDB];

    const int tid  = threadIdx.x;
    const int lane = tid & 63;
    const int wave = tid >> 6;
    const int rb = blockIdx.x >> 2;
    const int cbx = blockIdx.x & 3;
    const int m0 = rb * BM;
    const int n0 = cbx * BN;
    const int wr = (wave >> 1) * 64;
    const int wc = (wave & 1) * 64;
    const int l15 = lane & 15;
    const int lq  = lane >> 4;

    f32x4 acc[4][4];
#pragma unroll
    for (int i = 0; i < 4; ++i)
#pragma unroll
        for (int j = 0; j < 4; ++j)
            acc[i][j] = (f32x4){0.f, 0.f, 0.f, 0.f};

    const int arow = tid & 127;
    const int axq  = tid >> 7;

    for (int kt = 0; kt < KTOT / BK; ++kt) {
        const int k0  = kt * BK;
        const int xc0 = kt * (BK / NG);

        const f32x4 xv = *(const f32x4*)(X + (size_t)(m0 + arow) * IN_F + xc0 + 4 * axq);
        unsigned short* sArow = sA + arow * LDA + axq * 32;
#pragma unroll
        for (int j = 0; j < 4; ++j) {
            const float xs = xv[j] * SH;
            u32x4 pk;
#pragma unroll
            for (int g = 0; g < 8; g += 2) {
                float t0 = xs + (BC0N - g * SSTEP);
                float t1 = xs + (BC0N - (g + 1) * SSTEP);
                pk[g >> 1] = pack2bf(__builtin_amdgcn_exp2f(-t0 * t0),
                                     __builtin_amdgcn_exp2f(-t1 * t1));
            }
            *(u32x4*)(sArow + j * 8) = pk;
        }

#pragma unroll
        for (int p = 0; p < 8; ++p) {
            int id = p * 256 + tid;
            int n  = id & 127;
            int k4 = id >> 7;
            const float* wp = W + (size_t)(k0 + k4 * 4) * OUT_F + n0 + n;
            u32x2 v;
            v[0] = pack2bf(wp[0], wp[OUT_F]);
            v[1] = pack2bf(wp[2 * OUT_F], wp[3 * OUT_F]);
            *(u32x2*)(sB2 + n * LDB + k4 * 4) = v;
        }

        __syncthreads();

#pragma unroll
        for (int kk = 0; kk < BK; kk += 32) {
            short8 af[4], bfv[4];
#pragma unroll
            for (int i = 0; i < 4; ++i)
                af[i] = *(const short8*)(sA + (wr + i * 16 + l15) * LDA + kk + lq * 8);
#pragma unroll
            for (int i = 0; i < 4; ++i)
                bfv[i] = *(const short8*)(sB2 + (wc + i * 16 + l15) * LDB + kk + lq * 8);
#pragma unroll
            for (int i = 0; i < 4; ++i)
#pragma unroll
                for (int j = 0; j < 4; ++j)
                    acc[i][j] = __builtin_amdgcn_mfma_f32_16x16x32_bf16(af[i], bfv[j], acc[i][j], 0, 0, 0);
        }

        __syncthreads();
    }

#pragma unroll
    for (int i = 0; i < 4; ++i) {
        const int r0 = m0 + wr + i * 16 + lq * 4;
#pragma unroll
        for (int j = 0; j < 4; ++j) {
            const int c = n0 + wc + j * 16 + l15;
#pragma unroll
            for (int e = 0; e < 4; ++e)
                Out[(size_t)(r0 + e) * OUT_F + c] = acc[i][j][e];
        }
    }
}

extern "C" void kernel_launch(void* const* d_in, const int* in_sizes, int n_in,
                              void* d_out, int out_size, void* d_ws, size_t ws_size,
                              hipStream_t stream) {
    (void)in_sizes; (void)n_in; (void)out_size;
    const float* X = (const float*)d_in[0];
    // d_in[1] = grid (constants hardcoded: linspace(-2,2,8))
    const float* W = (const float*)d_in[2];
    float* Out = (float*)d_out;

    const size_t wt_bytes = (size_t)KTOT * OUT_F * sizeof(unsigned short); // 4 MB
    if (ws_size >= wt_bytes) {
        unsigned short* Wt = (unsigned short*)d_ws;
        wt_swizzle<<<dim3(KTOT * OUT_F / 8 / 256), 256, 0, stream>>>(W, Wt);
        gauss_gemm18<<<dim3((BATCH / 128) * (OUT_F / 256)), 512, 0, stream>>>(X, Wt, Out);
    } else {
        gauss_gemm_fb<<<dim3((BATCH / BM) * (OUT_F / BN)), 256, 0, stream>>>(X, W, Out);
    }
}